// Round 6
// baseline (99.300 us; speedup 1.0000x reference)
//
#include <hip/hip_runtime.h>

#define N 1024
#define D 256

typedef float f2_t __attribute__((ext_vector_type(2)));

// ---------------- prep ----------------
// 128 blocks x 8 rows, LDS-staged: coalesced float4 global loads, padded-LDS
// transpose, coalesced 8B stores (128B runs).
#define RI 8
#define LDW 260  // padded LDS row stride: %4==0 (float4 stores ok), +4 banks/row

__global__ __launch_bounds__(256) void prep3(
    const float* __restrict__ muX, const float* __restrict__ ls,
    float2* __restrict__ msT2) {
  const int i0 = blockIdx.x * RI;
  const int t = threadIdx.x;
  __shared__ float smu[RI][LDW];
  __shared__ float ssg[RI][LDW];
  __shared__ float sred[RI][32];
  __shared__ float rden[RI];
  const float4* mu4 = (const float4*)(muX + (size_t)i0 * D);
  const float4* ls4 = (const float4*)(ls + (size_t)i0 * D);
#pragma unroll
  for (int u = 0; u < 2; ++u) {
    const int idx = u * 256 + t;  // float4 index within the 8x256 row block
    const int row = idx >> 6, c4 = idx & 63;
    const float4 v = mu4[idx];
    *(float4*)&smu[row][c4 * 4] = v;
    const float4 e = ls4[idx];
    float4 x;
    x.x = __expf(e.x) + 5e-11f; x.y = __expf(e.y) + 5e-11f;  // eps folded
    x.z = __expf(e.z) + 5e-11f; x.w = __expf(e.w) + 5e-11f;
    *(float4*)&ssg[row][c4 * 4] = x;
  }
  __syncthreads();
  {
    const int r = t >> 5, q = t & 31;  // 32 lanes per row
    float s = 0.f;
#pragma unroll
    for (int k = 0; k < 8; ++k) {
      const float v = smu[r][q + 32 * k];
      s = fmaf(v, v, s);
    }
    sred[r][q] = s;
  }
  __syncthreads();
  if (t < RI) {
    float tot = 0.f;
    for (int u = 0; u < 32; ++u) tot += sred[t][u];
    rden[t] = 1.0f / fmaxf(sqrtf(tot), 1e-12f);  // F.normalize eps
  }
  __syncthreads();
#pragma unroll
  for (int pass = 0; pass < 8; ++pass) {
    const int f = pass * 256 + t;
    const int b = f & 1, il = (f >> 1) & 7, g = f >> 4;
    const int d = 2 * g + b;
    msT2[((size_t)g * N + i0 + il) * 2 + b] =
        make_float2(smu[il][d] * rden[il], ssg[il][d]);
  }
}

// ---------------- pair ----------------
// Triangular 2x128 tiles: 2304 blocks x 2 waves = 4.5 waves/SIMD.
// R6: output stores are NON-TEMPORAL (nt) so the ~10MB of C-writes stop
// evicting the 2MB msT working set from the 4MB per-XCD L2 (R5 FETCH_SIZE
// 9.2MB on a 2MB input = HBM re-fetch; loads were eating ~900cy HBM latency
// instead of ~250cy L2). unroll 8 batches ~760cy of compute per load-wait.
__global__ __launch_bounds__(128) void pair_kernel(
    const float4* __restrict__ msT4, float* __restrict__ out) {
  int L = blockIdx.x;
  int js = 0, base = 0;  // slab js has 64*(js+1) row-tiles of 2 rows
  while (L >= base + 64 * (js + 1)) { base += 64 * (js + 1); ++js; }
  const int ib = L - base;
  const int j0 = js * 128, i0 = ib * 2;
  const bool diag = (ib >= js * 64);  // tile straddles the diagonal
  const int j = j0 + threadIdx.x;

  float acc[2] = {0.f, 0.f};
  float p[2] = {1.f, 1.f};
  int ea[2] = {0, 0};

#pragma unroll 8
  for (int g = 0; g < D / 2; ++g) {
    const float4 jv = msT4[(size_t)g * N + j];
#pragma unroll
    for (int k = 0; k < 2; ++k) {
      const float4 iv = msT4[(size_t)g * N + i0 + k];  // uniform -> SGPR
      {
        const float sv = iv.y + jv.y;
        const float t0 = iv.x - jv.x;
        acc[k] = fmaf(t0 * t0, __builtin_amdgcn_rcpf(sv), acc[k]);
        p[k] *= sv;
      }
      {
        const float sv = iv.w + jv.w;
        const float t0 = iv.z - jv.z;
        acc[k] = fmaf(t0 * t0, __builtin_amdgcn_rcpf(sv), acc[k]);
        p[k] *= sv;
      }
    }
    if (g & 1) {  // renorm every 4 d's: |log2 s| <= ~8 -> exponent safe
#pragma unroll
      for (int k = 0; k < 2; ++k) {
        const int bb = __float_as_int(p[k]);
        ea[k] += bb >> 23;
        p[k] = __int_as_float((bb & 0x007fffff) | 0x3f800000);
      }
    }
  }

  constexpr float LN2 = 0.6931471805599453f;
  float v[2];
#pragma unroll
  for (int k = 0; k < 2; ++k) {
    const float lg2 = (float)(ea[k] - 127 * (D / 4)) + __log2f(p[k]);
    v[k] = -(acc[k] + LN2 * lg2);
  }

  if (!diag) {  // strictly-upper tile: unmasked direct + mirror, all nt
    __builtin_nontemporal_store(v[0], &out[(size_t)i0 * N + j]);
    __builtin_nontemporal_store(v[1], &out[(size_t)(i0 + 1) * N + j]);
    f2_t m;
    m.x = v[0]; m.y = v[1];
    __builtin_nontemporal_store(m, (f2_t*)(out + (size_t)j * N + i0));
  } else {  // diagonal tile: per-element masks
#pragma unroll
    for (int k = 0; k < 2; ++k) {
      const int i = i0 + k;
      if (j >= i) __builtin_nontemporal_store(v[k], &out[(size_t)i * N + j]);
      if (j > i) __builtin_nontemporal_store(v[k], &out[(size_t)j * N + i]);
    }
  }
}

extern "C" void kernel_launch(void* const* d_in, const int* in_sizes, int n_in,
                              void* d_out, int out_size, void* d_ws, size_t ws_size,
                              hipStream_t stream) {
  const float* muX = (const float*)d_in[0];
  const float* ls  = (const float*)d_in[1];
  float* out = (float*)d_out;
  float2* msT2 = (float2*)d_ws;  // [D/2][N][2] packed (mu,sig) pairs = 2 MB
  prep3<<<dim3(N / RI), dim3(256), 0, stream>>>(muX, ls, msT2);
  const int nblocks = 64 * (8 * 9 / 2);  // 2304 triangular 2x128 tiles
  pair_kernel<<<dim3(nblocks), dim3(128), 0, stream>>>((const float4*)msT2,
                                                       out);
}